// Round 6
// baseline (1559.336 us; speedup 1.0000x reference)
//
#include <hip/hip_runtime.h>
#include <hip/hip_bf16.h>
#include <cmath>

// ---------------------------------------------------------------------------
// IntegerDiscreteFlow on MI355X (gfx950)
// B=8192, D=1024, d2=512, N=2048, F=8 steps.
// State S (8192x1024 f32) updated in place; the [:, ::-1] reversal is an
// orientation bit (logical j <-> stored 1023-j), flipped each step.
// GEMMs in bf16 MFMA 16x16x32, fp32 accumulate.
// R2: XOR-swizzled LDS placement (bank conflicts -> 0).
// R5: ring-3 LDS pipeline (counted vmcnt across raw s_barrier).
// R6: 128x256 block tile for G1/G2 (wave-tile 64x128, 32 MFMA per barrier
//     per wave), 72 KB LDS, 2 blocks/CU. Proven 82.6 us G2 (832 TF).
// R7-R10: 8-phase ports and occupancy experiments all landed <= R6.
// R11: G3 split-K=2 via 128x128 ring-3 -> only ~330 TF. Lesson (with R6/R10):
//     perf ~= f(MFMA-per-barrier-phase x resident blocks/CU). 16-MFMA phases
//     need 4 blocks/CU; 32-MFMA phases work at 2.
// R12: G3 split-K GEMM rebuilt: 128x128, BK=64, 2-buffer LDS (64 KB ->
//     2 blocks/CU = grid's cap), 32 MFMA/wave/phase — the R6 regime.
//     BK=64 XOR family: stored chunk p = c ^ (row&7) (8 chunks/row), the
//     verified R7 gemm256 scheme (0 conflicts). Partials bit-identical to
//     R11 (same k order), so absmax stays 0. G1/G2 locked at R6 config.
// ---------------------------------------------------------------------------

typedef __bf16 bf16_t;
typedef bf16_t bf16x4 __attribute__((ext_vector_type(4)));
typedef bf16_t bf16x8 __attribute__((ext_vector_type(8)));
typedef float floatx4 __attribute__((ext_vector_type(4)));

#define BQ 8192
#define DD 1024
#define D2 512
#define NH 2048
#define NF 8

__device__ __forceinline__ void gload_lds16(const void* g, void* l) {
    __builtin_amdgcn_global_load_lds(
        (__attribute__((address_space(1))) void*)g,
        (__attribute__((address_space(3))) void*)l, 16, 0, 0);
}

// ---- weight convert+transpose: W (K x N f32, row-major) -> Wt (N x K bf16) --
__global__ __launch_bounds__(256)
void transpose_bf16(const float* __restrict__ W, bf16_t* __restrict__ Wt,
                    int K, int N) {
    __shared__ float tile[32][33];
    size_t fo = (size_t)blockIdx.z * K * N;
    int n0 = blockIdx.x * 32, k0 = blockIdx.y * 32;
    int tx = threadIdx.x & 31, ty = threadIdx.x >> 5;   // 32 x 8
    for (int i = 0; i < 4; i++)
        tile[ty + i*8][tx] = W[fo + (size_t)(k0 + ty + i*8) * N + n0 + tx];
    __syncthreads();
    for (int i = 0; i < 4; i++)
        Wt[fo + (size_t)(n0 + ty + i*8) * K + k0 + tx] = (bf16_t)tile[tx][ty + i*8];
}

// ---- fused: S = x (f32 copy) and Ab = bf16(xa) for step 0 ----
__global__ __launch_bounds__(256)
void init_SA(const float4* __restrict__ x, float4* __restrict__ S,
             bf16_t* __restrict__ Ab) {
    int idx = blockIdx.x * blockDim.x + threadIdx.x;   // over BQ*DD/4 = 2M
    float4 v = x[idx];
    S[idx] = v;
    int col4 = idx & (DD/4 - 1);                       // 0..255 (j = col4*4)
    if (col4 < D2/4) {
        int m = idx >> 8;
        bf16x4 p;
        p[0] = (bf16_t)v.x; p[1] = (bf16_t)v.y;
        p[2] = (bf16_t)v.z; p[3] = (bf16_t)v.w;
        ((bf16x4*)Ab)[(size_t)m * (D2/4) + col4] = p;
    }
}

// ---- G1/G2 GEMM, ring-3 LDS pipeline (R6 config, proven 832 TF) ----
// Block tile TM x TN, BK=32, 4 waves (2x2), wave-tile (TM/2) x (TN/2).
// MODE 0: Cout = bf16( leaky_relu(acc + bias[n]) )
template<int MODE, int K, int TM, int TN, int MINW>
__global__ __launch_bounds__(256, MINW)
void gemm_kernel(const bf16_t* __restrict__ A, const bf16_t* __restrict__ Bt,
                 const float* __restrict__ bias,
                 bf16_t* __restrict__ Cout, int N)
{
    constexpr int IM   = TM / 32;          // i-fragments per wave
    constexpr int JN   = TN / 32;          // j-fragments per wave
    constexpr int NA   = TM / 64;          // A DMA instrs per tile
    constexpr int NBD  = TN / 64;          // B DMA instrs per tile
    constexpr int NDMA = NA + NBD;         // DMA instrs per tile
    constexpr int T    = K / 32;           // K-tiles
    static_assert((T - 1) % 3 == 0, "pipeline triple-unroll needs (T-1)%3==0");
    static_assert(JN % 4 == 0, "bff processed in groups of 4");

    __shared__ __align__(16) bf16_t As[3][TM * 32];
    __shared__ __align__(16) bf16_t Bs[3][TN * 32];

    const int tid  = threadIdx.x;
    const int lane = tid & 63;
    const int wave = tid >> 6;
    const int wm   = wave >> 1;            // 0..1
    const int wn   = wave & 1;             // 0..1
    const int m0   = blockIdx.y * TM;
    const int n0   = blockIdx.x * TN;

    const int srow = tid >> 2;
    const int sq   = ((tid & 3) ^ ((srow >> 1) & 3)) * 8;
    const bf16_t* agp = A  + (size_t)(m0 + srow) * K + sq;
    const bf16_t* bgp = Bt + (size_t)(n0 + srow) * K + sq;

    floatx4 acc[IM][JN];
#pragma unroll
    for (int i = 0; i < IM; i++)
#pragma unroll
        for (int j = 0; j < JN; j++)
            acc[i][j] = (floatx4){0.f, 0.f, 0.f, 0.f};

    const int fr  = lane & 15;
    const int fp8 = ((lane >> 4) ^ ((lane >> 1) & 3)) * 8;

#define ISSUE_TILE(NB)                                                       \
    {                                                                        \
        _Pragma("unroll")                                                    \
        for (int u = 0; u < NA; u++)                                         \
            gload_lds16(agp + (size_t)(u*64) * K, &As[NB][u*2048 + tid*8]);  \
        _Pragma("unroll")                                                    \
        for (int u = 0; u < NBD; u++)                                        \
            gload_lds16(bgp + (size_t)(u*64) * K, &Bs[NB][u*2048 + tid*8]);  \
        agp += 32; bgp += 32;                                                \
    }

#define COMPUTE(CB)                                                          \
    {                                                                        \
        bf16x8 af[IM];                                                       \
        _Pragma("unroll")                                                    \
        for (int i = 0; i < IM; i++)                                         \
            af[i] = *(const bf16x8*)&As[CB][(wm*(TM/2) + i*16 + fr)*32 + fp8];\
        _Pragma("unroll")                                                    \
        for (int g2 = 0; g2 < JN/4; g2++) {                                  \
            bf16x8 bff[4];                                                   \
            _Pragma("unroll")                                                \
            for (int j = 0; j < 4; j++)                                      \
                bff[j] = *(const bf16x8*)                                    \
                    &Bs[CB][(wn*(TN/2) + (g2*4+j)*16 + fr)*32 + fp8];        \
            _Pragma("unroll")                                                \
            for (int i = 0; i < IM; i++)                                     \
                _Pragma("unroll")                                            \
                for (int j = 0; j < 4; j++)                                  \
                    acc[i][g2*4+j] = __builtin_amdgcn_mfma_f32_16x16x32_bf16(\
                                    af[i], bff[j], acc[i][g2*4+j], 0, 0, 0); \
        }                                                                    \
    }

#define PIPE_STEP(NB, CB)                                                    \
    {                                                                        \
        ISSUE_TILE(NB);                                                      \
        __builtin_amdgcn_s_waitcnt(0x0F70 | NDMA);  /* prev tile landed */   \
        __builtin_amdgcn_s_barrier();                                        \
        COMPUTE(CB);                                                         \
    }

    // prologue: tile 0 -> buf 0
    ISSUE_TILE(0);

    // steady state: tiles 3g+1, 3g+2, 3g+3 -> bufs 1, 2, 0
#pragma unroll 1
    for (int g = 0; g < (T - 1) / 3; ++g) {
        PIPE_STEP(1, 0);
        PIPE_STEP(2, 1);
        PIPE_STEP(0, 2);
    }
    // tail: compute tile T-1, which lives in buf 0
    __builtin_amdgcn_s_waitcnt(0x0F70);            // vmcnt(0)
    __builtin_amdgcn_s_barrier();
    COMPUTE(0);

#undef PIPE_STEP
#undef COMPUTE
#undef ISSUE_TILE

    // epilogue: C[row, col], col = lane&15, row = (lane>>4)*4 + r (m89 layout)
    const int ccol  = lane & 15;
    const int crow4 = (lane >> 4) * 4;
#pragma unroll
    for (int j = 0; j < JN; j++) {
        int col = n0 + wn*(TN/2) + j*16 + ccol;
        float bj = bias[col];
#pragma unroll
        for (int i = 0; i < IM; i++) {
#pragma unroll
            for (int r = 0; r < 4; r++) {
                int row = m0 + wm*(TM/2) + i*16 + crow4 + r;
                float v = acc[i][j][r] + bj;
                v = v >= 0.f ? v : 0.01f * v;
                Cout[(size_t)row * N + col] = (bf16_t)v;
            }
        }
    }
}

// ---------------------------------------------------------------------------
// G3 split-K GEMM: 128x128 tile, BK=64, 2-buffer LDS (64 KB -> 2 blocks/CU),
// 4 waves (2x2, wave-tile 64x64), 32 MFMA/wave per barrier phase.
// blockIdx.z selects K-half (KDEP=1024); f32 partials -> Pout[z*BQ*N ...].
// Loop: { ISSUE(t+1 -> b^1); COMPUTE(t, b) [2 k-slices]; vmcnt(0); barrier }.
// Swizzle (BK=64, 8 chunks/row): stored position p = c ^ (row&7); staging
// thread t fetches global chunk q = (t&7) ^ ((t>>3)&7), LDS dst linear;
// fragment read chunk (ks*4 + qh) ^ (lane&7) — the verified R7 scheme.
// K accumulation order identical to BK=32 (slices ascending) -> partials
// bit-identical to R11.
// ---------------------------------------------------------------------------
template<int KSTR, int KDEP>
__global__ __launch_bounds__(256, 2)
void gemm3_kernel(const bf16_t* __restrict__ A, const bf16_t* __restrict__ Bt,
                  float* __restrict__ Pout, int N)
{
    constexpr int T = KDEP / 64;           // 16 K-tiles
    static_assert(T >= 2, "need >=2 K-tiles");

    __shared__ __align__(16) bf16_t As[2][128 * 64];   // 16 KB each
    __shared__ __align__(16) bf16_t Bs[2][128 * 64];

    const int tid  = threadIdx.x;
    const int lane = tid & 63;
    const int wave = tid >> 6;
    const int wm   = wave >> 1;            // 0..1
    const int wn   = wave & 1;             // 0..1
    const int m0   = blockIdx.y * 128;
    const int n0   = blockIdx.x * 128;
    const int koff = blockIdx.z * KDEP;

    // staging: 8 DMA instrs per tile (4 A-slabs + 4 B-slabs of 32 rows).
    // thread t -> row t>>3 within slab, fetches chunk q = (t&7) ^ (row&7);
    // LDS dst linear at t*16B (=> stored position (t&7) = q ^ (row&7)).
    const int srow = tid >> 3;             // 0..31
    const int sq   = ((tid & 7) ^ (srow & 7)) * 8;
    const bf16_t* agp = A  + (size_t)(m0 + srow) * KSTR + koff + sq;
    const bf16_t* bgp = Bt + (size_t)(n0 + srow) * KSTR + koff + sq;

    floatx4 acc[4][4];
#pragma unroll
    for (int i = 0; i < 4; i++)
#pragma unroll
        for (int j = 0; j < 4; j++)
            acc[i][j] = (floatx4){0.f, 0.f, 0.f, 0.f};

    // fragment read: row = base + fr, chunk (ks*4+qh) ^ (row&7) = ... ^ l7
    const int fr = lane & 15;
    const int l7 = lane & 7;
    const int qh = lane >> 4;
    const int c0 = ((qh    ) ^ l7) * 8;    // ks=0 chunk position (elems)
    const int c1 = ((qh + 4) ^ l7) * 8;    // ks=1

#define ISSUE_TILE3(NB)                                                      \
    {                                                                        \
        _Pragma("unroll")                                                    \
        for (int u = 0; u < 4; u++)                                          \
            gload_lds16(agp + (size_t)(u*32) * KSTR, &As[NB][u*2048 + tid*8]);\
        _Pragma("unroll")                                                    \
        for (int u = 0; u < 4; u++)                                          \
            gload_lds16(bgp + (size_t)(u*32) * KSTR, &Bs[NB][u*2048 + tid*8]);\
        agp += 64; bgp += 64;                                                \
    }

#define COMPUTE3(CB)                                                         \
    {                                                                        \
        _Pragma("unroll")                                                    \
        for (int ks = 0; ks < 2; ks++) {                                     \
            const int cc = ks ? c1 : c0;                                     \
            bf16x8 af[4], bff[4];                                            \
            _Pragma("unroll")                                                \
            for (int i = 0; i < 4; i++)                                      \
                af[i] = *(const bf16x8*)                                     \
                    &As[CB][(wm*64 + i*16 + fr)*64 + cc];                    \
            _Pragma("unroll")                                                \
            for (int j = 0; j < 4; j++)                                      \
                bff[j] = *(const bf16x8*)                                    \
                    &Bs[CB][(wn*64 + j*16 + fr)*64 + cc];                    \
            _Pragma("unroll")                                                \
            for (int i = 0; i < 4; i++)                                      \
                _Pragma("unroll")                                            \
                for (int j = 0; j < 4; j++)                                  \
                    acc[i][j] = __builtin_amdgcn_mfma_f32_16x16x32_bf16(     \
                                    af[i], bff[j], acc[i][j], 0, 0, 0);      \
        }                                                                    \
    }

    // prologue: tile 0 -> buf 0, drain, barrier
    ISSUE_TILE3(0);
    __builtin_amdgcn_s_waitcnt(0x0F70);            // vmcnt(0)
    __builtin_amdgcn_s_barrier();

#pragma unroll 1
    for (int tau = 0; tau < T; ++tau) {
        if (tau + 1 < T) ISSUE_TILE3((tau + 1) & 1);
        COMPUTE3(tau & 1);
        if (tau + 1 < T) {
            __builtin_amdgcn_s_waitcnt(0x0F70);    // t+1 landed (hidden)
            __builtin_amdgcn_s_barrier();          // WAR + visibility
        }
    }

#undef COMPUTE3
#undef ISSUE_TILE3

    // epilogue: f32 partials (m89 layout: col = lane&15, row = qh*4 + r)
    float* P = Pout + (size_t)blockIdx.z * BQ * N;
    const int ccol  = lane & 15;
    const int crow4 = (lane >> 4) * 4;
#pragma unroll
    for (int j = 0; j < 4; j++) {
        int col = n0 + wn*64 + j*16 + ccol;
#pragma unroll
        for (int i = 0; i < 4; i++) {
#pragma unroll
            for (int r = 0; r < 4; r++) {
                int row = m0 + wm*64 + i*16 + crow4 + r;
                P[(size_t)row * N + col] = acc[i][j][r];
            }
        }
    }
}

// ---- G3 epilogue: t = P0 + P1 + b3; S[slot] += rint(t); Ab = reverse ----
__global__ __launch_bounds__(256)
void g3_epilogue(const float* __restrict__ P, const float* __restrict__ b3,
                 float* __restrict__ S, bf16_t* __restrict__ Ab, int rflag)
{
    int idx = blockIdx.x * blockDim.x + threadIdx.x;   // over BQ*D2/4 = 1M
    int row = idx >> 7;                                // D2/4 = 128 per row
    int c4  = (idx & 127) * 4;
    float4 p0 = ((const float4*)P)[idx];
    float4 p1 = ((const float4*)(P + (size_t)BQ * D2))[idx];
    float4 bb = ((const float4*)b3)[idx & 127];
    float t0 = p0.x + p1.x + bb.x;
    float t1 = p0.y + p1.y + bb.y;
    float t2 = p0.z + p1.z + bb.z;
    float t3 = p0.w + p1.w + bb.w;
    const float tv[4] = {t0, t1, t2, t3};
#pragma unroll
    for (int e = 0; e < 4; ++e) {
        int col  = c4 + e;
        int slot = rflag ? (511 - col) : (512 + col);
        float nv = S[(size_t)row * DD + slot] + rintf(tv[e]);
        S[(size_t)row * DD + slot] = nv;
        Ab[(size_t)row * D2 + (511 - col)] = (bf16_t)nv;
    }
}

// ---- final discretized-logistic NLL reduction ----
__global__ __launch_bounds__(256)
void reduce_nll(const float* __restrict__ S, const float* __restrict__ mean,
                const float* __restrict__ log_scale, float* __restrict__ out)
{
    float local = 0.f;
    const int total = BQ * DD;
    for (int idx = blockIdx.x * blockDim.x + threadIdx.x; idx < total;
         idx += gridDim.x * blockDim.x) {
        int j = idx & (DD - 1);
        float z  = S[idx];
        float mu = mean[j];
        float sc = expf(log_scale[j]);
        float ua = (z + 0.5f - mu) / sc;
        float ub = (z - 0.5f - mu) / sc;
        float la = fminf(ua, 0.f) - log1pf(expf(-fabsf(ua)));
        float lb = fminf(ub, 0.f) - log1pf(expf(-fabsf(ub)));
        float lp = la + logf(1.0f - expf(lb - la) + 1e-8f);
        local += lp;
    }
    __shared__ float red[256];
    red[threadIdx.x] = local;
    __syncthreads();
    for (int s = 128; s > 0; s >>= 1) {
        if (threadIdx.x < s) red[threadIdx.x] += red[threadIdx.x + s];
        __syncthreads();
    }
    if (threadIdx.x == 0) atomicAdd(out, -red[0] * (1.0f / (float)BQ));
}

extern "C" void kernel_launch(void* const* d_in, const int* in_sizes, int n_in,
                              void* d_out, int out_size, void* d_ws, size_t ws_size,
                              hipStream_t stream)
{
    const float* x   = (const float*)d_in[0];
    const float* W1  = (const float*)d_in[1];
    const float* b1  = (const float*)d_in[2];
    const float* W2  = (const float*)d_in[3];
    const float* b2  = (const float*)d_in[4];
    const float* W3  = (const float*)d_in[5];
    const float* b3  = (const float*)d_in[6];
    const float* mean = (const float*)d_in[7];
    const float* lsc  = (const float*)d_in[8];

    char* ws = (char*)d_ws;
    bf16_t* Wt1 = (bf16_t*)ws; ws += (size_t)NF * NH * D2 * 2;   // 16 MB (NxK = 2048x512)
    bf16_t* Wt2 = (bf16_t*)ws; ws += (size_t)NF * NH * NH * 2;   // 64 MB
    bf16_t* Wt3 = (bf16_t*)ws; ws += (size_t)NF * D2 * NH * 2;   // 16 MB (512x2048)
    float*  S   = (float*)ws;  ws += (size_t)BQ * DD * 4;        // 32 MB
    bf16_t* Ab  = (bf16_t*)ws; ws += (size_t)BQ * D2 * 2;        //  8 MB
    bf16_t* H1  = (bf16_t*)ws; ws += (size_t)BQ * NH * 2;        // 32 MB
    bf16_t* H2  = (bf16_t*)ws;                                   // 32 MB  (total 200 MB)
    float*  P3  = (float*)H1;   // G3 split-K partials (2 x 16 MB) alias H1:
                                // H1 is dead between G2 (reads it) and the
                                // next step's G1 (writes it).

    hipMemsetAsync(d_out, 0, sizeof(float), stream);

    dim3 blk(256);
    // W1: (K=512, N=2048) -> Wt1 (2048x512)
    transpose_bf16<<<dim3(NH/32, D2/32, NF), blk, 0, stream>>>(W1, Wt1, D2, NH);
    // W2: (2048, 2048)
    transpose_bf16<<<dim3(NH/32, NH/32, NF), blk, 0, stream>>>(W2, Wt2, NH, NH);
    // W3: (K=2048, N=512) -> Wt3 (512x2048)
    transpose_bf16<<<dim3(D2/32, NH/32, NF), blk, 0, stream>>>(W3, Wt3, NH, D2);

    init_SA<<<BQ * DD / 4 / 256, blk, 0, stream>>>((const float4*)x, (float4*)S, Ab);

    for (int f = 0; f < NF; ++f) {
        int r = f & 1;
        // G1: (8192 x 512) @ (512 x 2048) -> H1   [128x256 ring-3, 512 blocks]
        gemm_kernel<0, D2, 128, 256, 2><<<dim3(NH/256, BQ/128), blk, 0, stream>>>(
            Ab, Wt1 + (size_t)f * NH * D2, b1 + (size_t)f * NH, H1, NH);
        // G2: (8192 x 2048) @ (2048 x 2048) -> H2 [128x256 ring-3, 512 blocks]
        gemm_kernel<0, NH, 128, 256, 2><<<dim3(NH/256, BQ/128), blk, 0, stream>>>(
            H1, Wt2 + (size_t)f * NH * NH, b2 + (size_t)f * NH, H2, NH);
        // G3: (8192 x 2048) @ (2048 x 512) split-K=2, 128x128 BK=64 2-buf,
        //     grid (4,64,2) = 512 blocks; f32 partials -> P3 (aliases H1)
        gemm3_kernel<NH, 1024><<<dim3(D2/128, BQ/128, 2), blk, 0, stream>>>(
            H2, Wt3 + (size_t)f * D2 * NH, P3, D2);
        // G3 epilogue: sum partials + bias, rint, update S, emit next A
        g3_epilogue<<<BQ * D2 / 4 / 256, blk, 0, stream>>>(
            P3, b3 + (size_t)f * D2, S, Ab, r);
    }

    reduce_nll<<<2048, blk, 0, stream>>>(S, mean, lsc, (float*)d_out);
}

// Round 7
// 1535.727 us; speedup vs baseline: 1.0154x; 1.0154x over previous
//
#include <hip/hip_runtime.h>
#include <hip/hip_bf16.h>
#include <cmath>

// ---------------------------------------------------------------------------
// IntegerDiscreteFlow on MI355X (gfx950)
// B=8192, D=1024, d2=512, N=2048, F=8 steps.
// State S (8192x1024 f32) updated in place; the [:, ::-1] reversal is an
// orientation bit (logical j <-> stored 1023-j), flipped each step.
// GEMMs in bf16 MFMA 16x16x32, fp32 accumulate.
// R2: XOR-swizzled LDS placement (bank conflicts -> 0).
// R5: ring-3 LDS pipeline (counted vmcnt across raw s_barrier).
// R6: 128x256 block tile for G1/G2 (wave-tile 64x128, 32 MFMA per barrier
//     per wave), 72 KB LDS, 2 blocks/CU. Proven 82.6 us G2 (832 TF).
// R7-R12 family model (all measured):
//     128x256 ring-3 @2 blk/CU: 832 TF | 128x128 2buf BK32 @4 blk/CU: 759 TF
//     128x128 ring-3 @2 blk/CU: ~330   | 128x128 2buf BK64 @2 blk/CU: ~300
//     Only configs measured to work: R6's, and R10's gemm2b at 4 blocks/CU.
//     Derived-config transfers failed twice; this round transfers a MEASURED
//     kernel verbatim instead.
// R13: G3 split-K=4 (KDEP=512) on the verbatim R10 gemm2b structure:
//     grid (4,64,4) = 1024 blocks = 4/CU — exactly the measured 759-TF
//     regime. Partials in bf16 (4 x 8 MB = 32 MB, alias H1; err ~0.002
//     << rint margin; split-K reordering already absmax-0 in R11).
//     g3_epilogue sums 4 partials + bias, rint, updates S, emits Ab.
// ---------------------------------------------------------------------------

typedef __bf16 bf16_t;
typedef bf16_t bf16x4 __attribute__((ext_vector_type(4)));
typedef bf16_t bf16x8 __attribute__((ext_vector_type(8)));
typedef float floatx4 __attribute__((ext_vector_type(4)));

#define BQ 8192
#define DD 1024
#define D2 512
#define NH 2048
#define NF 8

__device__ __forceinline__ void gload_lds16(const void* g, void* l) {
    __builtin_amdgcn_global_load_lds(
        (__attribute__((address_space(1))) void*)g,
        (__attribute__((address_space(3))) void*)l, 16, 0, 0);
}

// ---- weight convert+transpose: W (K x N f32, row-major) -> Wt (N x K bf16) --
__global__ __launch_bounds__(256)
void transpose_bf16(const float* __restrict__ W, bf16_t* __restrict__ Wt,
                    int K, int N) {
    __shared__ float tile[32][33];
    size_t fo = (size_t)blockIdx.z * K * N;
    int n0 = blockIdx.x * 32, k0 = blockIdx.y * 32;
    int tx = threadIdx.x & 31, ty = threadIdx.x >> 5;   // 32 x 8
    for (int i = 0; i < 4; i++)
        tile[ty + i*8][tx] = W[fo + (size_t)(k0 + ty + i*8) * N + n0 + tx];
    __syncthreads();
    for (int i = 0; i < 4; i++)
        Wt[fo + (size_t)(n0 + ty + i*8) * K + k0 + tx] = (bf16_t)tile[tx][ty + i*8];
}

// ---- fused: S = x (f32 copy) and Ab = bf16(xa) for step 0 ----
__global__ __launch_bounds__(256)
void init_SA(const float4* __restrict__ x, float4* __restrict__ S,
             bf16_t* __restrict__ Ab) {
    int idx = blockIdx.x * blockDim.x + threadIdx.x;   // over BQ*DD/4 = 2M
    float4 v = x[idx];
    S[idx] = v;
    int col4 = idx & (DD/4 - 1);                       // 0..255 (j = col4*4)
    if (col4 < D2/4) {
        int m = idx >> 8;
        bf16x4 p;
        p[0] = (bf16_t)v.x; p[1] = (bf16_t)v.y;
        p[2] = (bf16_t)v.z; p[3] = (bf16_t)v.w;
        ((bf16x4*)Ab)[(size_t)m * (D2/4) + col4] = p;
    }
}

// ---- G1/G2 GEMM, ring-3 LDS pipeline (R6 config, proven 832 TF) ----
// Block tile TM x TN, BK=32, 4 waves (2x2), wave-tile (TM/2) x (TN/2).
// MODE 0: Cout = bf16( leaky_relu(acc + bias[n]) )
template<int MODE, int K, int TM, int TN, int MINW>
__global__ __launch_bounds__(256, MINW)
void gemm_kernel(const bf16_t* __restrict__ A, const bf16_t* __restrict__ Bt,
                 const float* __restrict__ bias,
                 bf16_t* __restrict__ Cout, int N)
{
    constexpr int IM   = TM / 32;          // i-fragments per wave
    constexpr int JN   = TN / 32;          // j-fragments per wave
    constexpr int NA   = TM / 64;          // A DMA instrs per tile
    constexpr int NBD  = TN / 64;          // B DMA instrs per tile
    constexpr int NDMA = NA + NBD;         // DMA instrs per tile
    constexpr int T    = K / 32;           // K-tiles
    static_assert((T - 1) % 3 == 0, "pipeline triple-unroll needs (T-1)%3==0");
    static_assert(JN % 4 == 0, "bff processed in groups of 4");

    __shared__ __align__(16) bf16_t As[3][TM * 32];
    __shared__ __align__(16) bf16_t Bs[3][TN * 32];

    const int tid  = threadIdx.x;
    const int lane = tid & 63;
    const int wave = tid >> 6;
    const int wm   = wave >> 1;            // 0..1
    const int wn   = wave & 1;             // 0..1
    const int m0   = blockIdx.y * TM;
    const int n0   = blockIdx.x * TN;

    const int srow = tid >> 2;
    const int sq   = ((tid & 3) ^ ((srow >> 1) & 3)) * 8;
    const bf16_t* agp = A  + (size_t)(m0 + srow) * K + sq;
    const bf16_t* bgp = Bt + (size_t)(n0 + srow) * K + sq;

    floatx4 acc[IM][JN];
#pragma unroll
    for (int i = 0; i < IM; i++)
#pragma unroll
        for (int j = 0; j < JN; j++)
            acc[i][j] = (floatx4){0.f, 0.f, 0.f, 0.f};

    const int fr  = lane & 15;
    const int fp8 = ((lane >> 4) ^ ((lane >> 1) & 3)) * 8;

#define ISSUE_TILE(NB)                                                       \
    {                                                                        \
        _Pragma("unroll")                                                    \
        for (int u = 0; u < NA; u++)                                         \
            gload_lds16(agp + (size_t)(u*64) * K, &As[NB][u*2048 + tid*8]);  \
        _Pragma("unroll")                                                    \
        for (int u = 0; u < NBD; u++)                                        \
            gload_lds16(bgp + (size_t)(u*64) * K, &Bs[NB][u*2048 + tid*8]);  \
        agp += 32; bgp += 32;                                                \
    }

#define COMPUTE(CB)                                                          \
    {                                                                        \
        bf16x8 af[IM];                                                       \
        _Pragma("unroll")                                                    \
        for (int i = 0; i < IM; i++)                                         \
            af[i] = *(const bf16x8*)&As[CB][(wm*(TM/2) + i*16 + fr)*32 + fp8];\
        _Pragma("unroll")                                                    \
        for (int g2 = 0; g2 < JN/4; g2++) {                                  \
            bf16x8 bff[4];                                                   \
            _Pragma("unroll")                                                \
            for (int j = 0; j < 4; j++)                                      \
                bff[j] = *(const bf16x8*)                                    \
                    &Bs[CB][(wn*(TN/2) + (g2*4+j)*16 + fr)*32 + fp8];        \
            _Pragma("unroll")                                                \
            for (int i = 0; i < IM; i++)                                     \
                _Pragma("unroll")                                            \
                for (int j = 0; j < 4; j++)                                  \
                    acc[i][g2*4+j] = __builtin_amdgcn_mfma_f32_16x16x32_bf16(\
                                    af[i], bff[j], acc[i][g2*4+j], 0, 0, 0); \
        }                                                                    \
    }

#define PIPE_STEP(NB, CB)                                                    \
    {                                                                        \
        ISSUE_TILE(NB);                                                      \
        __builtin_amdgcn_s_waitcnt(0x0F70 | NDMA);  /* prev tile landed */   \
        __builtin_amdgcn_s_barrier();                                        \
        COMPUTE(CB);                                                         \
    }

    // prologue: tile 0 -> buf 0
    ISSUE_TILE(0);

    // steady state: tiles 3g+1, 3g+2, 3g+3 -> bufs 1, 2, 0
#pragma unroll 1
    for (int g = 0; g < (T - 1) / 3; ++g) {
        PIPE_STEP(1, 0);
        PIPE_STEP(2, 1);
        PIPE_STEP(0, 2);
    }
    // tail: compute tile T-1, which lives in buf 0
    __builtin_amdgcn_s_waitcnt(0x0F70);            // vmcnt(0)
    __builtin_amdgcn_s_barrier();
    COMPUTE(0);

#undef PIPE_STEP
#undef COMPUTE
#undef ISSUE_TILE

    // epilogue: C[row, col], col = lane&15, row = (lane>>4)*4 + r (m89 layout)
    const int ccol  = lane & 15;
    const int crow4 = (lane >> 4) * 4;
#pragma unroll
    for (int j = 0; j < JN; j++) {
        int col = n0 + wn*(TN/2) + j*16 + ccol;
        float bj = bias[col];
#pragma unroll
        for (int i = 0; i < IM; i++) {
#pragma unroll
            for (int r = 0; r < 4; r++) {
                int row = m0 + wm*(TM/2) + i*16 + crow4 + r;
                float v = acc[i][j][r] + bj;
                v = v >= 0.f ? v : 0.01f * v;
                Cout[(size_t)row * N + col] = (bf16_t)v;
            }
        }
    }
}

// ---------------------------------------------------------------------------
// G3 split-K GEMM: verbatim R10 gemm2b structure (128x128, BK=32, 2-buffer
// 32 KB LDS, 4 waves 2x2, measured 759 TF at 4 blocks/CU) + split-K koff and
// bf16 partial store. blockIdx.z selects the K-quarter (KDEP=512, T=16).
// Loop: { ISSUE(t+1 -> b^1); COMPUTE(t, b); vmcnt(0); barrier; }.
// Pout[z*BQ*D2 + row*D2 + col] = bf16(acc) (partials summed in f32 by the
// epilogue kernel; bf16 partial error ~0.002 << the rint 0.5 margin).
// ---------------------------------------------------------------------------
template<int KSTR, int KDEP>
__global__ __launch_bounds__(256, 2)
void gemm3s_kernel(const bf16_t* __restrict__ A, const bf16_t* __restrict__ Bt,
                   bf16_t* __restrict__ Pout)
{
    constexpr int TM = 128, TN = 128;
    constexpr int IM = TM / 32;            // 4
    constexpr int JN = TN / 32;            // 4
    constexpr int NA = TM / 64;            // 2
    constexpr int NBD = TN / 64;           // 2
    constexpr int T  = KDEP / 32;          // 16
    static_assert(T >= 2, "need >=2 K-tiles");
    static_assert(JN % 4 == 0, "bff processed in groups of 4");

    __shared__ __align__(16) bf16_t As[2][TM * 32];
    __shared__ __align__(16) bf16_t Bs[2][TN * 32];

    const int tid  = threadIdx.x;
    const int lane = tid & 63;
    const int wave = tid >> 6;
    const int wm   = wave >> 1;            // 0..1
    const int wn   = wave & 1;             // 0..1
    const int m0   = blockIdx.y * TM;
    const int n0   = blockIdx.x * TN;
    const int koff = blockIdx.z * KDEP;

    const int srow = tid >> 2;
    const int sq   = ((tid & 3) ^ ((srow >> 1) & 3)) * 8;
    const bf16_t* agp = A  + (size_t)(m0 + srow) * KSTR + koff + sq;
    const bf16_t* bgp = Bt + (size_t)(n0 + srow) * KSTR + koff + sq;

    floatx4 acc[IM][JN];
#pragma unroll
    for (int i = 0; i < IM; i++)
#pragma unroll
        for (int j = 0; j < JN; j++)
            acc[i][j] = (floatx4){0.f, 0.f, 0.f, 0.f};

    const int fr  = lane & 15;
    const int fp8 = ((lane >> 4) ^ ((lane >> 1) & 3)) * 8;

#define ISSUE_TILE3(NB)                                                      \
    {                                                                        \
        _Pragma("unroll")                                                    \
        for (int u = 0; u < NA; u++)                                         \
            gload_lds16(agp + (size_t)(u*64) * KSTR, &As[NB][u*2048 + tid*8]);\
        _Pragma("unroll")                                                    \
        for (int u = 0; u < NBD; u++)                                        \
            gload_lds16(bgp + (size_t)(u*64) * KSTR, &Bs[NB][u*2048 + tid*8]);\
        agp += 32; bgp += 32;                                                \
    }

#define COMPUTE3(CB)                                                         \
    {                                                                        \
        bf16x8 af[IM];                                                       \
        _Pragma("unroll")                                                    \
        for (int i = 0; i < IM; i++)                                         \
            af[i] = *(const bf16x8*)&As[CB][(wm*(TM/2) + i*16 + fr)*32 + fp8];\
        _Pragma("unroll")                                                    \
        for (int g2 = 0; g2 < JN/4; g2++) {                                  \
            bf16x8 bff[4];                                                   \
            _Pragma("unroll")                                                \
            for (int j = 0; j < 4; j++)                                      \
                bff[j] = *(const bf16x8*)                                    \
                    &Bs[CB][(wn*(TN/2) + (g2*4+j)*16 + fr)*32 + fp8];        \
            _Pragma("unroll")                                                \
            for (int i = 0; i < IM; i++)                                     \
                _Pragma("unroll")                                            \
                for (int j = 0; j < 4; j++)                                  \
                    acc[i][g2*4+j] = __builtin_amdgcn_mfma_f32_16x16x32_bf16(\
                                    af[i], bff[j], acc[i][g2*4+j], 0, 0, 0); \
        }                                                                    \
    }

    // prologue: tile 0 -> buf 0, drain, barrier
    ISSUE_TILE3(0);
    __builtin_amdgcn_s_waitcnt(0x0F70);            // vmcnt(0)
    __builtin_amdgcn_s_barrier();

#pragma unroll 1
    for (int tau = 0; tau < T; ++tau) {
        if (tau + 1 < T) ISSUE_TILE3((tau + 1) & 1);
        COMPUTE3(tau & 1);
        if (tau + 1 < T) {
            __builtin_amdgcn_s_waitcnt(0x0F70);    // t+1 landed (hidden)
            __builtin_amdgcn_s_barrier();          // WAR + visibility
        }
    }

#undef COMPUTE3
#undef ISSUE_TILE3

    // epilogue: bf16 partials (m89 layout: col = lane&15, row = qh*4 + r)
    bf16_t* P = Pout + (size_t)blockIdx.z * BQ * D2;
    const int ccol  = lane & 15;
    const int crow4 = (lane >> 4) * 4;
#pragma unroll
    for (int j = 0; j < JN; j++) {
        int col = n0 + wn*(TN/2) + j*16 + ccol;
#pragma unroll
        for (int i = 0; i < IM; i++) {
#pragma unroll
            for (int r = 0; r < 4; r++) {
                int row = m0 + wm*(TM/2) + i*16 + crow4 + r;
                P[(size_t)row * D2 + col] = (bf16_t)acc[i][j][r];
            }
        }
    }
}

// ---- G3 epilogue: t = sum_z P_z + b3; S[slot] += rint(t); Ab = reverse ----
__global__ __launch_bounds__(256)
void g3_epilogue(const bf16_t* __restrict__ P, const float* __restrict__ b3,
                 float* __restrict__ S, bf16_t* __restrict__ Ab, int rflag)
{
    int idx = blockIdx.x * blockDim.x + threadIdx.x;   // over BQ*D2/4 = 1M
    int row = idx >> 7;                                // D2/4 = 128 per row
    int c4  = (idx & 127) * 4;
    bf16x4 p0 = ((const bf16x4*)(P                        ))[idx];
    bf16x4 p1 = ((const bf16x4*)(P + (size_t)1*BQ*D2))[idx];
    bf16x4 p2 = ((const bf16x4*)(P + (size_t)2*BQ*D2))[idx];
    bf16x4 p3 = ((const bf16x4*)(P + (size_t)3*BQ*D2))[idx];
    float4 bb = ((const float4*)b3)[idx & 127];
    float tv[4];
#pragma unroll
    for (int e = 0; e < 4; ++e)
        tv[e] = (float)p0[e] + (float)p1[e] + (float)p2[e] + (float)p3[e]
              + ((const float*)&bb)[e];
#pragma unroll
    for (int e = 0; e < 4; ++e) {
        int col  = c4 + e;
        int slot = rflag ? (511 - col) : (512 + col);
        float nv = S[(size_t)row * DD + slot] + rintf(tv[e]);
        S[(size_t)row * DD + slot] = nv;
        Ab[(size_t)row * D2 + (511 - col)] = (bf16_t)nv;
    }
}

// ---- final discretized-logistic NLL reduction ----
__global__ __launch_bounds__(256)
void reduce_nll(const float* __restrict__ S, const float* __restrict__ mean,
                const float* __restrict__ log_scale, float* __restrict__ out)
{
    float local = 0.f;
    const int total = BQ * DD;
    for (int idx = blockIdx.x * blockDim.x + threadIdx.x; idx < total;
         idx += gridDim.x * blockDim.x) {
        int j = idx & (DD - 1);
        float z  = S[idx];
        float mu = mean[j];
        float sc = expf(log_scale[j]);
        float ua = (z + 0.5f - mu) / sc;
        float ub = (z - 0.5f - mu) / sc;
        float la = fminf(ua, 0.f) - log1pf(expf(-fabsf(ua)));
        float lb = fminf(ub, 0.f) - log1pf(expf(-fabsf(ub)));
        float lp = la + logf(1.0f - expf(lb - la) + 1e-8f);
        local += lp;
    }
    __shared__ float red[256];
    red[threadIdx.x] = local;
    __syncthreads();
    for (int s = 128; s > 0; s >>= 1) {
        if (threadIdx.x < s) red[threadIdx.x] += red[threadIdx.x + s];
        __syncthreads();
    }
    if (threadIdx.x == 0) atomicAdd(out, -red[0] * (1.0f / (float)BQ));
}

extern "C" void kernel_launch(void* const* d_in, const int* in_sizes, int n_in,
                              void* d_out, int out_size, void* d_ws, size_t ws_size,
                              hipStream_t stream)
{
    const float* x   = (const float*)d_in[0];
    const float* W1  = (const float*)d_in[1];
    const float* b1  = (const float*)d_in[2];
    const float* W2  = (const float*)d_in[3];
    const float* b2  = (const float*)d_in[4];
    const float* W3  = (const float*)d_in[5];
    const float* b3  = (const float*)d_in[6];
    const float* mean = (const float*)d_in[7];
    const float* lsc  = (const float*)d_in[8];

    char* ws = (char*)d_ws;
    bf16_t* Wt1 = (bf16_t*)ws; ws += (size_t)NF * NH * D2 * 2;   // 16 MB (NxK = 2048x512)
    bf16_t* Wt2 = (bf16_t*)ws; ws += (size_t)NF * NH * NH * 2;   // 64 MB
    bf16_t* Wt3 = (bf16_t*)ws; ws += (size_t)NF * D2 * NH * 2;   // 16 MB (512x2048)
    float*  S   = (float*)ws;  ws += (size_t)BQ * DD * 4;        // 32 MB
    bf16_t* Ab  = (bf16_t*)ws; ws += (size_t)BQ * D2 * 2;        //  8 MB
    bf16_t* H1  = (bf16_t*)ws; ws += (size_t)BQ * NH * 2;        // 32 MB
    bf16_t* H2  = (bf16_t*)ws;                                   // 32 MB  (total 200 MB)
    bf16_t* P3  = H1;           // G3 split-K=4 bf16 partials (4 x 8 MB = 32
                                // MB) alias H1: dead between G2 and next G1.

    hipMemsetAsync(d_out, 0, sizeof(float), stream);

    dim3 blk(256);
    // W1: (K=512, N=2048) -> Wt1 (2048x512)
    transpose_bf16<<<dim3(NH/32, D2/32, NF), blk, 0, stream>>>(W1, Wt1, D2, NH);
    // W2: (2048, 2048)
    transpose_bf16<<<dim3(NH/32, NH/32, NF), blk, 0, stream>>>(W2, Wt2, NH, NH);
    // W3: (K=2048, N=512) -> Wt3 (512x2048)
    transpose_bf16<<<dim3(D2/32, NH/32, NF), blk, 0, stream>>>(W3, Wt3, NH, D2);

    init_SA<<<BQ * DD / 4 / 256, blk, 0, stream>>>((const float4*)x, (float4*)S, Ab);

    for (int f = 0; f < NF; ++f) {
        int r = f & 1;
        // G1: (8192 x 512) @ (512 x 2048) -> H1   [128x256 ring-3, 512 blocks]
        gemm_kernel<0, D2, 128, 256, 2><<<dim3(NH/256, BQ/128), blk, 0, stream>>>(
            Ab, Wt1 + (size_t)f * NH * D2, b1 + (size_t)f * NH, H1, NH);
        // G2: (8192 x 2048) @ (2048 x 2048) -> H2 [128x256 ring-3, 512 blocks]
        gemm_kernel<0, NH, 128, 256, 2><<<dim3(NH/256, BQ/128), blk, 0, stream>>>(
            H1, Wt2 + (size_t)f * NH * NH, b2 + (size_t)f * NH, H2, NH);
        // G3: (8192 x 2048) @ (2048 x 512) split-K=4 on verbatim-R10 gemm2b,
        //     grid (4,64,4) = 1024 blocks = 4/CU; bf16 partials -> P3 (=H1)
        gemm3s_kernel<NH, 512><<<dim3(D2/128, BQ/128, 4), blk, 0, stream>>>(
            H2, Wt3 + (size_t)f * D2 * NH, P3);
        // G3 epilogue: sum 4 partials + bias, rint, update S, emit next A
        g3_epilogue<<<BQ * D2 / 4 / 256, blk, 0, stream>>>(
            P3, b3 + (size_t)f * D2, S, Ab, r);
    }

    reduce_nll<<<2048, blk, 0, stream>>>(S, mean, lsc, (float*)d_out);
}

// Round 8
// 1477.937 us; speedup vs baseline: 1.0551x; 1.0391x over previous
//
#include <hip/hip_runtime.h>
#include <hip/hip_bf16.h>
#include <cmath>

// ---------------------------------------------------------------------------
// IntegerDiscreteFlow on MI355X (gfx950)
// B=8192, D=1024, d2=512, N=2048, F=8 steps.
// State S (8192x1024 f32) updated in place; the [:, ::-1] reversal is an
// orientation bit (logical j <-> stored 1023-j), flipped each step.
// GEMMs in bf16 MFMA 16x16x32, fp32 accumulate.
// R2: XOR-swizzled LDS placement (bank conflicts -> 0).
// R5: ring-3 LDS pipeline, DMA issued before s_waitcnt vmcnt(NDMA) + raw
//     s_barrier (loads stay in flight across the barrier).
// R6: 128x256 block tile for G1/G2 (wave-tile 64x128, 32 MFMA per barrier
//     per wave), 72 KB LDS, 2 blocks/CU. G3 stays 64x128 MODE-1 fused.
// R7-R13 (all measured <= R6 config; reverted):
//   - 8-phase 256x256 ports x2: 642-764 TF vs 832 (m232-class port failure)
//   - 128x128 @4 blk/CU: 759 TF; occupancy x2 bought +0% MfmaUtil
//   - G3 split-K x3 (ring-3/BK64/verbatim-2buf): 300-330 TF + epilogue
//     round-trip — all net-worse than monolithic 64x128 G3 (65 us).
//   Family ledger closes at fixed~110us, G1~23, G2~82.6, G3~65.
// R14: exact R6/R0 configuration + init_SA fusion (copy_x+prep_A one-pass,
//     ~4 us; absmax 0 across 4 prior runs). Best-known state, banked.
// ---------------------------------------------------------------------------

typedef __bf16 bf16_t;
typedef bf16_t bf16x4 __attribute__((ext_vector_type(4)));
typedef bf16_t bf16x8 __attribute__((ext_vector_type(8)));
typedef float floatx4 __attribute__((ext_vector_type(4)));

#define BQ 8192
#define DD 1024
#define D2 512
#define NH 2048
#define NF 8

__device__ __forceinline__ void gload_lds16(const void* g, void* l) {
    __builtin_amdgcn_global_load_lds(
        (__attribute__((address_space(1))) void*)g,
        (__attribute__((address_space(3))) void*)l, 16, 0, 0);
}

// ---- weight convert+transpose: W (K x N f32, row-major) -> Wt (N x K bf16) --
__global__ __launch_bounds__(256)
void transpose_bf16(const float* __restrict__ W, bf16_t* __restrict__ Wt,
                    int K, int N) {
    __shared__ float tile[32][33];
    size_t fo = (size_t)blockIdx.z * K * N;
    int n0 = blockIdx.x * 32, k0 = blockIdx.y * 32;
    int tx = threadIdx.x & 31, ty = threadIdx.x >> 5;   // 32 x 8
    for (int i = 0; i < 4; i++)
        tile[ty + i*8][tx] = W[fo + (size_t)(k0 + ty + i*8) * N + n0 + tx];
    __syncthreads();
    for (int i = 0; i < 4; i++)
        Wt[fo + (size_t)(n0 + ty + i*8) * K + k0 + tx] = (bf16_t)tile[tx][ty + i*8];
}

// ---- fused: S = x (f32 copy) and Ab = bf16(xa) for step 0 ----
__global__ __launch_bounds__(256)
void init_SA(const float4* __restrict__ x, float4* __restrict__ S,
             bf16_t* __restrict__ Ab) {
    int idx = blockIdx.x * blockDim.x + threadIdx.x;   // over BQ*DD/4 = 2M
    float4 v = x[idx];
    S[idx] = v;
    int col4 = idx & (DD/4 - 1);                       // 0..255 (j = col4*4)
    if (col4 < D2/4) {
        int m = idx >> 8;
        bf16x4 p;
        p[0] = (bf16_t)v.x; p[1] = (bf16_t)v.y;
        p[2] = (bf16_t)v.z; p[3] = (bf16_t)v.w;
        ((bf16x4*)Ab)[(size_t)m * (D2/4) + col4] = p;
    }
}

// ---- GEMM: C = A(MxK bf16) @ B, B given transposed as Bt (NxK bf16) ----
// Block tile TM x TN, BK=32, ring-3 LDS pipeline, 4 waves (2x2), wave-tile
// (TM/2) x (TN/2).
// MODE 0: out = bf16( leaky_relu(acc + bias[n]) )
// MODE 1: S[m, slot(n)] += rint(acc + bias[n]); Abn[m, 511-n] = new value
template<int MODE, int K, int TM, int TN, int MINW>
__global__ __launch_bounds__(256, MINW)
void gemm_kernel(const bf16_t* __restrict__ A, const bf16_t* __restrict__ Bt,
                 const float* __restrict__ bias,
                 bf16_t* __restrict__ Cout, float* __restrict__ S,
                 bf16_t* __restrict__ Abn,
                 int N, int rflag)
{
    constexpr int IM   = TM / 32;          // i-fragments per wave
    constexpr int JN   = TN / 32;          // j-fragments per wave
    constexpr int NA   = TM / 64;          // A DMA instrs per tile
    constexpr int NBD  = TN / 64;          // B DMA instrs per tile
    constexpr int NDMA = NA + NBD;         // DMA instrs per tile
    constexpr int T    = K / 32;           // K-tiles
    static_assert((T - 1) % 3 == 0, "pipeline triple-unroll needs (T-1)%3==0");
    static_assert(JN % 4 == 0, "bff processed in groups of 4");

    __shared__ __align__(16) bf16_t As[3][TM * 32];
    __shared__ __align__(16) bf16_t Bs[3][TN * 32];

    const int tid  = threadIdx.x;
    const int lane = tid & 63;
    const int wave = tid >> 6;
    const int wm   = wave >> 1;            // 0..1
    const int wn   = wave & 1;             // 0..1
    const int m0   = blockIdx.y * TM;
    const int n0   = blockIdx.x * TN;

    // Staging map (per DMA instr u): thread t -> row u*64 + (t>>2), chunk
    // position p = t&3; global chunk fetched q = p ^ ((row>>1)&3) (XOR
    // swizzle; u*64 doesn't change (row>>1)&3). LDS dst = u*2048 + t*8 elems.
    const int srow = tid >> 2;
    const int sq   = ((tid & 3) ^ ((srow >> 1) & 3)) * 8;
    const bf16_t* agp = A  + (size_t)(m0 + srow) * K + sq;
    const bf16_t* bgp = Bt + (size_t)(n0 + srow) * K + sq;

    floatx4 acc[IM][JN];
#pragma unroll
    for (int i = 0; i < IM; i++)
#pragma unroll
        for (int j = 0; j < JN; j++)
            acc[i][j] = (floatx4){0.f, 0.f, 0.f, 0.f};

    // Fragment read: row rr = base + (lane&15) (base mult. of 16), chunk
    // c = lane>>4 stored at position c ^ ((rr>>1)&3) = c ^ ((lane>>1)&3).
    const int fr  = lane & 15;
    const int fp8 = ((lane >> 4) ^ ((lane >> 1) & 3)) * 8;

#define ISSUE_TILE(NB)                                                       \
    {                                                                        \
        _Pragma("unroll")                                                    \
        for (int u = 0; u < NA; u++)                                         \
            gload_lds16(agp + (size_t)(u*64) * K, &As[NB][u*2048 + tid*8]);  \
        _Pragma("unroll")                                                    \
        for (int u = 0; u < NBD; u++)                                        \
            gload_lds16(bgp + (size_t)(u*64) * K, &Bs[NB][u*2048 + tid*8]);  \
        agp += 32; bgp += 32;                                                \
    }

// bff processed in two groups of 4 to cap live registers at JN=8.
#define COMPUTE(CB)                                                          \
    {                                                                        \
        bf16x8 af[IM];                                                       \
        _Pragma("unroll")                                                    \
        for (int i = 0; i < IM; i++)                                         \
            af[i] = *(const bf16x8*)&As[CB][(wm*(TM/2) + i*16 + fr)*32 + fp8];\
        _Pragma("unroll")                                                    \
        for (int g2 = 0; g2 < JN/4; g2++) {                                  \
            bf16x8 bff[4];                                                   \
            _Pragma("unroll")                                                \
            for (int j = 0; j < 4; j++)                                      \
                bff[j] = *(const bf16x8*)                                    \
                    &Bs[CB][(wn*(TN/2) + (g2*4+j)*16 + fr)*32 + fp8];        \
            _Pragma("unroll")                                                \
            for (int i = 0; i < IM; i++)                                     \
                _Pragma("unroll")                                            \
                for (int j = 0; j < 4; j++)                                  \
                    acc[i][g2*4+j] = __builtin_amdgcn_mfma_f32_16x16x32_bf16(\
                                    af[i], bff[j], acc[i][g2*4+j], 0, 0, 0); \
        }                                                                    \
    }

#define PIPE_STEP(NB, CB)                                                    \
    {                                                                        \
        ISSUE_TILE(NB);                                                      \
        __builtin_amdgcn_s_waitcnt(0x0F70 | NDMA);  /* prev tile landed */   \
        __builtin_amdgcn_s_barrier();                                        \
        COMPUTE(CB);                                                         \
    }

    // prologue: tile 0 -> buf 0
    ISSUE_TILE(0);

    // steady state: tiles it = 3g+1, 3g+2, 3g+3 -> bufs 1, 2, 0
#pragma unroll 1
    for (int g = 0; g < (T - 1) / 3; ++g) {
        PIPE_STEP(1, 0);
        PIPE_STEP(2, 1);
        PIPE_STEP(0, 2);
    }
    // tail: compute tile T-1, which lives in buf (T-1)%3 == 0
    __builtin_amdgcn_s_waitcnt(0x0F70);            // vmcnt(0)
    __builtin_amdgcn_s_barrier();
    COMPUTE(0);

#undef PIPE_STEP
#undef COMPUTE
#undef ISSUE_TILE

    // epilogue: C[row, col], col = lane&15, row = (lane>>4)*4 + r  (m89 layout)
    const int ccol  = lane & 15;
    const int crow4 = (lane >> 4) * 4;
#pragma unroll
    for (int j = 0; j < JN; j++) {
        int col = n0 + wn*(TN/2) + j*16 + ccol;
        float bj = bias[col];
        if (MODE == 0) {
#pragma unroll
            for (int i = 0; i < IM; i++) {
#pragma unroll
                for (int r = 0; r < 4; r++) {
                    int row = m0 + wm*(TM/2) + i*16 + crow4 + r;
                    float v = acc[i][j][r] + bj;
                    v = v >= 0.f ? v : 0.01f * v;
                    Cout[(size_t)row * N + col] = (bf16_t)v;
                }
            }
        } else {
            int slot = rflag ? (511 - col) : (512 + col);
            int aj   = 511 - col;          // next step's xa = reverse(yb)
#pragma unroll
            for (int i = 0; i < IM; i++) {
#pragma unroll
                for (int r = 0; r < 4; r++) {
                    int row = m0 + wm*(TM/2) + i*16 + crow4 + r;
                    float t = acc[i][j][r] + bj;
                    float nv = S[(size_t)row * DD + slot] + rintf(t);
                    S[(size_t)row * DD + slot] = nv;
                    Abn[(size_t)row * D2 + aj] = (bf16_t)nv;
                }
            }
        }
    }
}

// ---- final discretized-logistic NLL reduction ----
__global__ __launch_bounds__(256)
void reduce_nll(const float* __restrict__ S, const float* __restrict__ mean,
                const float* __restrict__ log_scale, float* __restrict__ out)
{
    float local = 0.f;
    const int total = BQ * DD;
    for (int idx = blockIdx.x * blockDim.x + threadIdx.x; idx < total;
         idx += gridDim.x * blockDim.x) {
        int j = idx & (DD - 1);
        float z  = S[idx];
        float mu = mean[j];
        float sc = expf(log_scale[j]);
        float ua = (z + 0.5f - mu) / sc;
        float ub = (z - 0.5f - mu) / sc;
        float la = fminf(ua, 0.f) - log1pf(expf(-fabsf(ua)));
        float lb = fminf(ub, 0.f) - log1pf(expf(-fabsf(ub)));
        float lp = la + logf(1.0f - expf(lb - la) + 1e-8f);
        local += lp;
    }
    __shared__ float red[256];
    red[threadIdx.x] = local;
    __syncthreads();
    for (int s = 128; s > 0; s >>= 1) {
        if (threadIdx.x < s) red[threadIdx.x] += red[threadIdx.x + s];
        __syncthreads();
    }
    if (threadIdx.x == 0) atomicAdd(out, -red[0] * (1.0f / (float)BQ));
}

extern "C" void kernel_launch(void* const* d_in, const int* in_sizes, int n_in,
                              void* d_out, int out_size, void* d_ws, size_t ws_size,
                              hipStream_t stream)
{
    const float* x   = (const float*)d_in[0];
    const float* W1  = (const float*)d_in[1];
    const float* b1  = (const float*)d_in[2];
    const float* W2  = (const float*)d_in[3];
    const float* b2  = (const float*)d_in[4];
    const float* W3  = (const float*)d_in[5];
    const float* b3  = (const float*)d_in[6];
    const float* mean = (const float*)d_in[7];
    const float* lsc  = (const float*)d_in[8];

    char* ws = (char*)d_ws;
    bf16_t* Wt1 = (bf16_t*)ws; ws += (size_t)NF * NH * D2 * 2;   // 16 MB (NxK = 2048x512)
    bf16_t* Wt2 = (bf16_t*)ws; ws += (size_t)NF * NH * NH * 2;   // 64 MB
    bf16_t* Wt3 = (bf16_t*)ws; ws += (size_t)NF * D2 * NH * 2;   // 16 MB (512x2048)
    float*  S   = (float*)ws;  ws += (size_t)BQ * DD * 4;        // 32 MB
    bf16_t* Ab  = (bf16_t*)ws; ws += (size_t)BQ * D2 * 2;        //  8 MB
    bf16_t* H1  = (bf16_t*)ws; ws += (size_t)BQ * NH * 2;        // 32 MB
    bf16_t* H2  = (bf16_t*)ws;                                   // 32 MB  (total 200 MB)

    hipMemsetAsync(d_out, 0, sizeof(float), stream);

    dim3 blk(256);
    // W1: (K=512, N=2048) -> Wt1 (2048x512)
    transpose_bf16<<<dim3(NH/32, D2/32, NF), blk, 0, stream>>>(W1, Wt1, D2, NH);
    // W2: (2048, 2048)
    transpose_bf16<<<dim3(NH/32, NH/32, NF), blk, 0, stream>>>(W2, Wt2, NH, NH);
    // W3: (K=2048, N=512) -> Wt3 (512x2048)
    transpose_bf16<<<dim3(D2/32, NH/32, NF), blk, 0, stream>>>(W3, Wt3, NH, D2);

    // fused S=x copy + step-0 A emit
    init_SA<<<BQ * DD / 4 / 256, blk, 0, stream>>>((const float4*)x, (float4*)S, Ab);

    for (int f = 0; f < NF; ++f) {
        int r = f & 1;
        // G1: (8192 x 512) @ (512 x 2048) -> H1   [128x256 tiles, 512 blocks]
        gemm_kernel<0, D2, 128, 256, 2><<<dim3(NH/256, BQ/128), blk, 0, stream>>>(
            Ab, Wt1 + (size_t)f * NH * D2, b1 + (size_t)f * NH, H1, nullptr,
            nullptr, NH, 0);
        // G2: (8192 x 2048) @ (2048 x 2048) -> H2 [128x256 tiles, 512 blocks]
        gemm_kernel<0, NH, 128, 256, 2><<<dim3(NH/256, BQ/128), blk, 0, stream>>>(
            H1, Wt2 + (size_t)f * NH * NH, b2 + (size_t)f * NH, H2, nullptr,
            nullptr, NH, 0);
        // G3: (8192 x 2048) @ (2048 x 512), 64x128 tiles -> S + next-A emit
        gemm_kernel<1, NH, 64, 128, 3><<<dim3(D2/128, BQ/64), blk, 0, stream>>>(
            H2, Wt3 + (size_t)f * D2 * NH, b3 + (size_t)f * D2, nullptr, S,
            Ab, D2, r);
    }

    reduce_nll<<<2048, blk, 0, stream>>>(S, mean, lsc, (float*)d_out);
}